// Round 2
// baseline (390.065 us; speedup 1.0000x reference)
//
#include <hip/hip_runtime.h>
#include <hip/hip_bf16.h>
#include <math.h>

typedef __attribute__((ext_vector_type(4))) float f32x4;
typedef __attribute__((ext_vector_type(8))) short bf16x8;

#define N_ROWS 8192
#define D 256
#define KSPLIT 4
#define KRANGE (N_ROWS / KSPLIT)   // 2048

__device__ __forceinline__ unsigned short f2bf(float f) {
    unsigned int u = __float_as_uint(f);
    unsigned int r = u + 0x7FFFu + ((u >> 16) & 1u);
    return (unsigned short)(r >> 16);
}

__device__ __forceinline__ float breduce_sum256(float v, float* sb) {
#pragma unroll
    for (int off = 32; off; off >>= 1) v += __shfl_down(v, off);
    int wid = threadIdx.x >> 6;
    __syncthreads();
    if ((threadIdx.x & 63) == 0) sb[wid] = v;
    __syncthreads();
    return sb[0] + sb[1] + sb[2] + sb[3];
}

// K1: logx = logmap0(x) -> L (d_out scratch). col0 = 0.
__global__ void k_logmap0(const float* __restrict__ x, float* __restrict__ L) {
    __shared__ float sb[4];
    int row = blockIdx.x, t = threadIdx.x;
    float xv = x[(size_t)row * D + t];
    float yv = (t >= 1) ? xv : 0.f;
    float ss = breduce_sum256(yv * yv, sb);
    float ynorm = fmaxf(sqrtf(ss), 1e-15f);
    float x0 = x[(size_t)row * D];
    float th = fmaxf(x0, 1.f + 1e-7f);
    float al = acoshf(th);
    L[(size_t)row * D + t] = (t >= 1) ? (al * yv / ynorm) : 0.f;
}

// K2: M2[k][j] = sum_m W_gcn[k][m] * W_att[m+1][j]
__global__ void k_M2(const float* __restrict__ Wg, const float* __restrict__ Wa,
                     float* __restrict__ M2) {
    int k = blockIdx.x, t = threadIdx.x;
    float acc = 0.f;
#pragma unroll 8
    for (int m = 0; m < 255; ++m)
        acc += Wg[k * 255 + m] * Wa[(m + 1) * 256 + t];
    M2[k * 256 + t] = acc;
}

// K3: h[i][j] = sum_k L[i][k+1] * M2[k][j]
__global__ void k_h(const float* __restrict__ L, const float* __restrict__ M2,
                    float* __restrict__ h) {
    __shared__ float Ls[8][256];
    int i0 = blockIdx.x * 8, t = threadIdx.x;
    for (int r = 0; r < 8; ++r) Ls[r][t] = L[(size_t)(i0 + r) * D + t];
    __syncthreads();
    float acc[8] = {0.f, 0.f, 0.f, 0.f, 0.f, 0.f, 0.f, 0.f};
#pragma unroll 4
    for (int k = 0; k < 255; ++k) {
        float m2 = M2[k * 256 + t];
#pragma unroll
        for (int r = 0; r < 8; ++r) acc[r] += Ls[r][k + 1] * m2;
    }
    for (int r = 0; r < 8; ++r) h[(size_t)(i0 + r) * D + t] = acc[r];
}

// K4: c[j] = h[j,:] . a_att[256:512]
__global__ void k_cvec(const float* __restrict__ h, const float* __restrict__ aatt,
                       float* __restrict__ cvec) {
    __shared__ float sb[4];
    int row = blockIdx.x, t = threadIdx.x;
    float v = h[(size_t)row * D + t] * aatt[256 + t];
    float s = breduce_sum256(v, sb);
    if (t == 0) cvec[row] = s;
}

__global__ void k_max(const float* __restrict__ cvec, float* __restrict__ Mval) {
    __shared__ float sb[4];
    int t = threadIdx.x;
    float m = -3.4e38f;
    for (int i = t; i < N_ROWS; i += 256) m = fmaxf(m, cvec[i]);
#pragma unroll
    for (int off = 32; off; off >>= 1) m = fmaxf(m, __shfl_down(m, off));
    if ((t & 63) == 0) sb[t >> 6] = m;
    __syncthreads();
    if (t == 0) Mval[0] = fmaxf(fmaxf(sb[0], sb[1]), fmaxf(sb[2], sb[3]));
}

__global__ void k_wexp(const float* __restrict__ cvec, const float* __restrict__ Mval,
                       float* __restrict__ wexp) {
    int i = blockIdx.x * 256 + threadIdx.x;
    if (i < N_ROWS) wexp[i] = expf(cvec[i] - Mval[0]);
}

// K5: GT[c][j] = bf16( wexp[j] * h[j][c] )   (256 x 8192)
__global__ void k_makeGT(const float* __restrict__ h, const float* __restrict__ wexp,
                         unsigned short* __restrict__ GT) {
    __shared__ unsigned short tile[64][72];
    int J0 = blockIdx.x * 64, C0 = blockIdx.y * 64;
    int t = threadIdx.x;
    int cc = t & 63, r4 = t >> 6;
#pragma unroll
    for (int s = 0; s < 16; ++s) {
        int jr = r4 + s * 4;
        float w = wexp[J0 + jr];
        float v = h[(size_t)(J0 + jr) * D + C0 + cc] * w;
        tile[jr][cc] = f2bf(v);
    }
    __syncthreads();
#pragma unroll
    for (int s = 0; s < 16; ++s) {
        int cr = r4 + s * 4;
        GT[(size_t)(C0 + cr) * N_ROWS + J0 + cc] = tile[cc][cr];
    }
}

__device__ __forceinline__ bf16x8 adj2bf(int4 a, int4 b) {
    bf16x8 r;
    r[0] = a.x ? (short)0x3F80 : (short)0;
    r[1] = a.y ? (short)0x3F80 : (short)0;
    r[2] = a.z ? (short)0x3F80 : (short)0;
    r[3] = a.w ? (short)0x3F80 : (short)0;
    r[4] = b.x ? (short)0x3F80 : (short)0;
    r[5] = b.y ? (short)0x3F80 : (short)0;
    r[6] = b.z ? (short)0x3F80 : (short)0;
    r[7] = b.w ? (short)0x3F80 : (short)0;
    return r;
}

__device__ __forceinline__ float masksum(int4 a, float4 w) {
    return (a.x ? w.x : 0.f) + (a.y ? w.y : 0.f) + (a.z ? w.z : 0.f) + (a.w ? w.w : 0.f);
}

// K6: register-direct masked GEMM with split-K.
// grid = (N_ROWS/32) * KSPLIT blocks, 256 thr (4 waves). BM=32, BN=256 (64/wave), BK=64.
// No LDS in main loop, no barriers: A (adj) and B (GT) fragments loaded straight to regs.
__global__ void __launch_bounds__(256, 4)
k_attreg(const int* __restrict__ adj, const unsigned short* __restrict__ GT,
         const float* __restrict__ wexp, float* __restrict__ part,
         float* __restrict__ rspart) {
    int tid = threadIdx.x;
    int rb = blockIdx.x & (N_ROWS / 32 - 1);   // 0..255
    int kb = blockIdx.x >> 8;                  // 0..KSPLIT-1
    int i0 = rb * 32;
    int kbeg = kb * KRANGE;
    int w = tid >> 6, l = tid & 63;
    const int lr = l & 15, lk = (l >> 4) * 8;

    const int* arow0 = adj + (size_t)(i0 + lr) * N_ROWS;
    const int* arow1 = arow0 + (size_t)16 * N_ROWS;
    const unsigned short* gcol0 = GT + (size_t)(w * 64 + 0 * 16 + lr) * N_ROWS;
    const unsigned short* gcol1 = GT + (size_t)(w * 64 + 1 * 16 + lr) * N_ROWS;
    const unsigned short* gcol2 = GT + (size_t)(w * 64 + 2 * 16 + lr) * N_ROWS;
    const unsigned short* gcol3 = GT + (size_t)(w * 64 + 3 * 16 + lr) * N_ROWS;

    f32x4 zero4 = {0.f, 0.f, 0.f, 0.f};
    f32x4 acc[2][4];
#pragma unroll
    for (int m = 0; m < 2; ++m)
#pragma unroll
        for (int n = 0; n < 4; ++n) acc[m][n] = zero4;
    float rs0 = 0.f, rs1 = 0.f;

    for (int kt = 0; kt < KRANGE / 64; ++kt) {
        int k0 = kbeg + kt * 64;
        // ---- ks = 0 phase (k0+lk .. k0+lk+7)
        {
            int ka = k0 + lk;
            int4 a00 = *(const int4*)(arow0 + ka);
            int4 a01 = *(const int4*)(arow0 + ka + 4);
            int4 a10 = *(const int4*)(arow1 + ka);
            int4 a11 = *(const int4*)(arow1 + ka + 4);
            float4 w0 = *(const float4*)(wexp + ka);
            float4 w1 = *(const float4*)(wexp + ka + 4);
            bf16x8 b0 = *(const bf16x8*)(gcol0 + ka);
            bf16x8 b1 = *(const bf16x8*)(gcol1 + ka);
            bf16x8 b2 = *(const bf16x8*)(gcol2 + ka);
            bf16x8 b3 = *(const bf16x8*)(gcol3 + ka);
            bf16x8 af0 = adj2bf(a00, a01);
            bf16x8 af1 = adj2bf(a10, a11);
            rs0 += masksum(a00, w0) + masksum(a01, w1);
            rs1 += masksum(a10, w0) + masksum(a11, w1);
            acc[0][0] = __builtin_amdgcn_mfma_f32_16x16x32_bf16(af0, b0, acc[0][0], 0, 0, 0);
            acc[0][1] = __builtin_amdgcn_mfma_f32_16x16x32_bf16(af0, b1, acc[0][1], 0, 0, 0);
            acc[0][2] = __builtin_amdgcn_mfma_f32_16x16x32_bf16(af0, b2, acc[0][2], 0, 0, 0);
            acc[0][3] = __builtin_amdgcn_mfma_f32_16x16x32_bf16(af0, b3, acc[0][3], 0, 0, 0);
            acc[1][0] = __builtin_amdgcn_mfma_f32_16x16x32_bf16(af1, b0, acc[1][0], 0, 0, 0);
            acc[1][1] = __builtin_amdgcn_mfma_f32_16x16x32_bf16(af1, b1, acc[1][1], 0, 0, 0);
            acc[1][2] = __builtin_amdgcn_mfma_f32_16x16x32_bf16(af1, b2, acc[1][2], 0, 0, 0);
            acc[1][3] = __builtin_amdgcn_mfma_f32_16x16x32_bf16(af1, b3, acc[1][3], 0, 0, 0);
        }
        // ---- ks = 1 phase (k0+32+lk ..)
        {
            int ka = k0 + 32 + lk;
            int4 a00 = *(const int4*)(arow0 + ka);
            int4 a01 = *(const int4*)(arow0 + ka + 4);
            int4 a10 = *(const int4*)(arow1 + ka);
            int4 a11 = *(const int4*)(arow1 + ka + 4);
            float4 w0 = *(const float4*)(wexp + ka);
            float4 w1 = *(const float4*)(wexp + ka + 4);
            bf16x8 b0 = *(const bf16x8*)(gcol0 + ka);
            bf16x8 b1 = *(const bf16x8*)(gcol1 + ka);
            bf16x8 b2 = *(const bf16x8*)(gcol2 + ka);
            bf16x8 b3 = *(const bf16x8*)(gcol3 + ka);
            bf16x8 af0 = adj2bf(a00, a01);
            bf16x8 af1 = adj2bf(a10, a11);
            rs0 += masksum(a00, w0) + masksum(a01, w1);
            rs1 += masksum(a10, w0) + masksum(a11, w1);
            acc[0][0] = __builtin_amdgcn_mfma_f32_16x16x32_bf16(af0, b0, acc[0][0], 0, 0, 0);
            acc[0][1] = __builtin_amdgcn_mfma_f32_16x16x32_bf16(af0, b1, acc[0][1], 0, 0, 0);
            acc[0][2] = __builtin_amdgcn_mfma_f32_16x16x32_bf16(af0, b2, acc[0][2], 0, 0, 0);
            acc[0][3] = __builtin_amdgcn_mfma_f32_16x16x32_bf16(af0, b3, acc[0][3], 0, 0, 0);
            acc[1][0] = __builtin_amdgcn_mfma_f32_16x16x32_bf16(af1, b0, acc[1][0], 0, 0, 0);
            acc[1][1] = __builtin_amdgcn_mfma_f32_16x16x32_bf16(af1, b1, acc[1][1], 0, 0, 0);
            acc[1][2] = __builtin_amdgcn_mfma_f32_16x16x32_bf16(af1, b2, acc[1][2], 0, 0, 0);
            acc[1][3] = __builtin_amdgcn_mfma_f32_16x16x32_bf16(af1, b3, acc[1][3], 0, 0, 0);
        }
    }

    // rowsum: all 4 waves computed identical rs; reduce lanes sharing lr, wave 0 writes.
    rs0 += __shfl_xor(rs0, 16); rs0 += __shfl_xor(rs0, 32);
    rs1 += __shfl_xor(rs1, 16); rs1 += __shfl_xor(rs1, 32);
    if (w == 0 && l < 16) {
        rspart[(size_t)kb * N_ROWS + i0 + l] = rs0;
        rspart[(size_t)kb * N_ROWS + i0 + 16 + l] = rs1;
    }

    // C write (layout: col=lane&15, row=(lane>>4)*4+reg)
    float* pbase = part + (size_t)kb * N_ROWS * D;
#pragma unroll
    for (int m = 0; m < 2; ++m)
#pragma unroll
        for (int n = 0; n < 4; ++n) {
            int orow = i0 + m * 16 + ((l >> 4) << 2);
            int ocol = (w << 6) + (n << 4) + lr;
            float* op = pbase + (size_t)orow * D + ocol;
#pragma unroll
            for (int v = 0; v < 4; ++v) op[(size_t)v * D] = acc[m][n][v];
        }
}

// K7: fused split-K reduce + epilogue (divide, elu, proj, logmap0, sigmoid, expmap0)
__global__ void k_final2(const float* __restrict__ part, const float* __restrict__ rspart,
                         float* __restrict__ out) {
    __shared__ float sb[4];
    int row = blockIdx.x, t = threadIdx.x;
    float raw = 0.f, rs = 0.f;
#pragma unroll
    for (int kb = 0; kb < KSPLIT; ++kb) {
        raw += part[((size_t)kb * N_ROWS + row) * D + t];
        rs += rspart[(size_t)kb * N_ROWS + row];
    }
    float hp = raw / rs;
    float ey = 0.f;
    if (t >= 1) ey = (hp > 0.f) ? hp : expm1f(hp);
    float ss = breduce_sum256(ey * ey, sb);
    float x0 = sqrtf(1.f + ss);
    float th = fmaxf(x0, 1.f + 1e-7f);
    float al = acoshf(th);
    float yn = fmaxf(sqrtf(ss), 1e-15f);
    float u = (t >= 1) ? (al * ey / yn) : 0.f;
    float s = 1.f / (1.f + expf(-u));
    float s2 = (t >= 1) ? s * s : 0.f;
    float ssn = breduce_sum256(s2, sb);
    float xn = fmaxf(sqrtf(ssn), 1e-15f);
    float sh = sinhf(xn);
    float yf = (t >= 1) ? (sh * s / xn) : 0.f;
    float sy = breduce_sum256(yf * yf, sb);
    float res = (t == 0) ? sqrtf(1.f + sy) : yf;
    out[(size_t)row * D + t] = res;
}

extern "C" void kernel_launch(void* const* d_in, const int* in_sizes, int n_in,
                              void* d_out, int out_size, void* d_ws, size_t ws_size,
                              hipStream_t stream) {
    const float* x    = (const float*)d_in[0];
    const int*   adj  = (const int*)d_in[1];
    const float* Wg   = (const float*)d_in[3];
    const float* Wa   = (const float*)d_in[4];
    const float* aatt = (const float*)d_in[5];
    float* out = (float*)d_out;

    // ws layout (part overlays h, which is dead by the time k_attreg runs):
    char* wsb = (char*)d_ws;
    float*          M2     = (float*)(wsb);                    // 256 KB
    float*          h      = (float*)(wsb + 0x0040000);        // 8 MB (dead after makeGT/cvec)
    float*          part   = (float*)(wsb + 0x0040000);        // KSPLIT*8 MB = 32 MB
    unsigned short* GT     = (unsigned short*)(wsb + 0x2040000); // 4 MB
    float*          cvec   = (float*)(wsb + 0x2440000);        // 32 KB
    float*          wexp   = (float*)(wsb + 0x2448000);        // 32 KB
    float*          rspart = (float*)(wsb + 0x2450000);        // 128 KB
    float*          Mval   = (float*)(wsb + 0x2470000);        // 4 B

    k_logmap0<<<N_ROWS, 256, 0, stream>>>(x, out);            // L in d_out
    k_M2<<<255, 256, 0, stream>>>(Wg, Wa, M2);
    k_h<<<N_ROWS / 8, 256, 0, stream>>>(out, M2, h);
    k_cvec<<<N_ROWS, 256, 0, stream>>>(h, aatt, cvec);
    k_max<<<1, 256, 0, stream>>>(cvec, Mval);
    k_wexp<<<N_ROWS / 256, 256, 0, stream>>>(cvec, Mval, wexp);
    k_makeGT<<<dim3(N_ROWS / 64, 4), 256, 0, stream>>>(h, wexp, GT);
    k_attreg<<<(N_ROWS / 32) * KSPLIT, 256, 0, stream>>>(adj, GT, wexp, part, rspart);
    k_final2<<<N_ROWS, 256, 0, stream>>>(part, rspart, out);
}

// Round 3
// 220.787 us; speedup vs baseline: 1.7667x; 1.7667x over previous
//
#include <hip/hip_runtime.h>
#include <hip/hip_bf16.h>
#include <math.h>

typedef __attribute__((ext_vector_type(4))) float f32x4;
typedef __attribute__((ext_vector_type(8))) short bf16x8;

#define N_ROWS 8192
#define D 256
#define KSPLIT 4
#define KRANGE (N_ROWS / KSPLIT)   // 2048
#define MSHIFT 16.0f

__device__ __forceinline__ unsigned short f2bf(float f) {
    unsigned int u = __float_as_uint(f);
    unsigned int r = u + 0x7FFFu + ((u >> 16) & 1u);
    return (unsigned short)(r >> 16);
}

__device__ __forceinline__ float breduce_sum256(float v, float* sb) {
#pragma unroll
    for (int off = 32; off; off >>= 1) v += __shfl_down(v, off);
    int wid = threadIdx.x >> 6;
    __syncthreads();
    if ((threadIdx.x & 63) == 0) sb[wid] = v;
    __syncthreads();
    return sb[0] + sb[1] + sb[2] + sb[3];
}

__device__ __forceinline__ void dma16(const void* g, void* l) {
    __builtin_amdgcn_global_load_lds(
        (const __attribute__((address_space(1))) unsigned int*)g,
        (__attribute__((address_space(3))) unsigned int*)l, 16, 0, 0);
}

__device__ __forceinline__ bf16x8 adj2bf(int4 a, int4 b) {
    bf16x8 r;
    r[0] = a.x ? (short)0x3F80 : (short)0;
    r[1] = a.y ? (short)0x3F80 : (short)0;
    r[2] = a.z ? (short)0x3F80 : (short)0;
    r[3] = a.w ? (short)0x3F80 : (short)0;
    r[4] = b.x ? (short)0x3F80 : (short)0;
    r[5] = b.y ? (short)0x3F80 : (short)0;
    r[6] = b.z ? (short)0x3F80 : (short)0;
    r[7] = b.w ? (short)0x3F80 : (short)0;
    return r;
}

// K2: M2[k][j] = sum_m W_gcn[k][m] * W_att[m+1][j]
__global__ void k_M2(const float* __restrict__ Wg, const float* __restrict__ Wa,
                     float* __restrict__ M2) {
    int k = blockIdx.x, t = threadIdx.x;
    float acc = 0.f;
#pragma unroll 8
    for (int m = 0; m < 255; ++m)
        acc += Wg[k * 255 + m] * Wa[(m + 1) * 256 + t];
    M2[k * 256 + t] = acc;
}

// K3: fused logmap0 + h-GEMV + cvec + wexp.
// h[i][j] = sum_k logx[i][k+1] * M2[k][j];  c[i] = h[i,:].a2;  wexp=exp(c-16)
__global__ void k_h(const float* __restrict__ x, const float* __restrict__ M2,
                    const float* __restrict__ aatt,
                    float* __restrict__ h, float* __restrict__ wexp,
                    unsigned short* __restrict__ wbf) {
    __shared__ float sb[4];
    __shared__ float Ls[8][256];
    int i0 = blockIdx.x * 8, t = threadIdx.x;
#pragma unroll
    for (int r = 0; r < 8; ++r) {
        float xv = x[(size_t)(i0 + r) * D + t];
        float yv = (t >= 1) ? xv : 0.f;
        float ss = breduce_sum256(yv * yv, sb);
        float ynorm = fmaxf(sqrtf(ss), 1e-15f);
        float x0 = x[(size_t)(i0 + r) * D];
        float th = fmaxf(x0, 1.f + 1e-7f);
        float al = acoshf(th);
        Ls[r][t] = (t >= 1) ? (al * yv / ynorm) : 0.f;
    }
    __syncthreads();
    float acc[8] = {0.f, 0.f, 0.f, 0.f, 0.f, 0.f, 0.f, 0.f};
#pragma unroll 4
    for (int k = 0; k < 255; ++k) {
        float m2 = M2[k * 256 + t];
#pragma unroll
        for (int r = 0; r < 8; ++r) acc[r] += Ls[r][k + 1] * m2;
    }
#pragma unroll
    for (int r = 0; r < 8; ++r) h[(size_t)(i0 + r) * D + t] = acc[r];
    float a2 = aatt[256 + t];
#pragma unroll
    for (int r = 0; r < 8; ++r) {
        float s = breduce_sum256(acc[r] * a2, sb);
        if (t == r) {
            float e = expf(s - MSHIFT);
            wexp[i0 + r] = e;
            wbf[i0 + r] = f2bf(e);
        }
    }
}

// K5: GT[c][j] = bf16( wexp[j] * h[j][c] )   (256 x 8192)
__global__ void k_makeGT(const float* __restrict__ h, const float* __restrict__ wexp,
                         unsigned short* __restrict__ GT) {
    __shared__ unsigned short tile[64][72];
    int J0 = blockIdx.x * 64, C0 = blockIdx.y * 64;
    int t = threadIdx.x;
    int cc = t & 63, r4 = t >> 6;
#pragma unroll
    for (int s = 0; s < 16; ++s) {
        int jr = r4 + s * 4;
        float w = wexp[J0 + jr];
        float v = h[(size_t)(J0 + jr) * D + C0 + cc] * w;
        tile[jr][cc] = f2bf(v);
    }
    __syncthreads();
#pragma unroll
    for (int s = 0; s < 16; ++s) {
        int cr = r4 + s * 4;
        GT[(size_t)(C0 + cr) * N_ROWS + J0 + cc] = tile[cc][cr];
    }
}

// K6: masked GEMM with split-K, global_load_lds staging + XOR-swizzled LDS.
// BM=32, BN=256, BK=64. 256 thr (4 waves). grid = 256 row-blocks * KSPLIT.
// rowsum folded in as an extra MFMA B-column (wexp bf16 on col 0).
__global__ void __launch_bounds__(256, 4)
k_attreg(const int* __restrict__ adj, const unsigned short* __restrict__ GT,
         const unsigned short* __restrict__ wbf, float* __restrict__ part,
         float* __restrict__ rspart) {
    __shared__ __align__(16) int As[32 * 64];             // 8 KB, k-swizzled rows (256 B)
    __shared__ __align__(16) unsigned short Bs[256 * 64]; // 32 KB, k-swizzled rows (128 B)
    const int tid = threadIdx.x;
    const int rb = blockIdx.x & 255;
    const int kb = blockIdx.x >> 8;
    const int i0 = rb * 32;
    const int kbeg = kb * KRANGE;
    const int w = tid >> 6, l = tid & 63;
    const int lr = l & 15, lk = (l >> 4) * 8;

    // ---- staging source pointers (pre-swizzled global addresses; LDS stays linear)
    // A inst a covers rows a*4..a*4+3; lane l -> row a*4+(l>>4), 16B granule (l&15)^(row&7)
    const int a0i = w * 2;
    const int arow0 = a0i * 4 + (l >> 4);
    const int arow1 = arow0 + 4;
    const int* srcA0 = adj + (size_t)(i0 + arow0) * N_ROWS + kbeg + (((l & 15) ^ (arow0 & 7)) << 2);
    const int* srcA1 = adj + (size_t)(i0 + arow1) * N_ROWS + kbeg + (((l & 15) ^ (arow1 & 7)) << 2);
    char* ldsA0 = (char*)As + a0i * 1024;
    char* ldsA1 = ldsA0 + 1024;
    // B inst j covers cols (w*8+j)*8..+7; lane l -> col base+(l>>3), granule (l&7)^(col&7)
    const unsigned short* srcB[8];
    char* ldsB0 = (char*)Bs + w * 8192;
#pragma unroll
    for (int j = 0; j < 8; ++j) {
        int col = (w * 8 + j) * 8 + (l >> 3);
        srcB[j] = GT + (size_t)col * N_ROWS + kbeg + (((l & 7) ^ (col & 7)) << 3);
    }
    const unsigned short* wptr = wbf + kbeg;

    f32x4 zero4 = {0.f, 0.f, 0.f, 0.f};
    f32x4 acc[2][4], acc_rs[2];
#pragma unroll
    for (int m = 0; m < 2; ++m) {
        acc_rs[m] = zero4;
#pragma unroll
        for (int n = 0; n < 4; ++n) acc[m][n] = zero4;
    }

    for (int kt = 0; kt < KRANGE / 64; ++kt) {
        if (kt) __syncthreads();
        // ---- DMA stage (10 wave-insts: 2 A + 8 B)
        dma16(srcA0 + kt * 64, ldsA0);
        dma16(srcA1 + kt * 64, ldsA1);
#pragma unroll
        for (int j = 0; j < 8; ++j)
            dma16(srcB[j] + kt * 64, ldsB0 + j * 1024);
        __syncthreads();   // drains vmcnt(0): DMA complete + visible
        // ---- compute
#pragma unroll
        for (int ks = 0; ks < 2; ++ks) {
            const int kbA = (ks * 32 + lk) * 4;
            const int kbB = (ks * 32 + lk) * 2;
            const int sw = (lr & 7) << 4;
            bf16x8 af0, af1;
            {
                const char* p = (const char*)As + lr * 256;
                int4 u = *(const int4*)(p + (kbA ^ sw));
                int4 v = *(const int4*)(p + ((kbA + 16) ^ sw));
                af0 = adj2bf(u, v);
            }
            {
                const char* p = (const char*)As + (16 + lr) * 256;
                int4 u = *(const int4*)(p + (kbA ^ sw));
                int4 v = *(const int4*)(p + ((kbA + 16) ^ sw));
                af1 = adj2bf(u, v);
            }
            bf16x8 bfr[4];
#pragma unroll
            for (int n = 0; n < 4; ++n) {
                const char* p = (const char*)Bs + (w * 64 + n * 16 + lr) * 128;
                bfr[n] = *(const bf16x8*)(p + (kbB ^ sw));
            }
            bf16x8 wf = {0, 0, 0, 0, 0, 0, 0, 0};
            if (lr == 0) wf = *(const bf16x8*)(wptr + kt * 64 + ks * 32 + lk);
#pragma unroll
            for (int n = 0; n < 4; ++n) {
                acc[0][n] = __builtin_amdgcn_mfma_f32_16x16x32_bf16(af0, bfr[n], acc[0][n], 0, 0, 0);
                acc[1][n] = __builtin_amdgcn_mfma_f32_16x16x32_bf16(af1, bfr[n], acc[1][n], 0, 0, 0);
            }
            acc_rs[0] = __builtin_amdgcn_mfma_f32_16x16x32_bf16(af0, wf, acc_rs[0], 0, 0, 0);
            acc_rs[1] = __builtin_amdgcn_mfma_f32_16x16x32_bf16(af1, wf, acc_rs[1], 0, 0, 0);
        }
    }

    // ---- rowsum write (col 0 of acc_rs; all waves identical, wave 0 writes)
    if (w == 0 && lr == 0) {
        int q = l >> 4;
#pragma unroll
        for (int m = 0; m < 2; ++m)
#pragma unroll
            for (int v = 0; v < 4; ++v)
                rspart[(size_t)kb * N_ROWS + i0 + m * 16 + q * 4 + v] = acc_rs[m][v];
    }

    // ---- C write (layout: col=lane&15, row=(lane>>4)*4+reg)
    float* pbase = part + (size_t)kb * N_ROWS * D;
#pragma unroll
    for (int m = 0; m < 2; ++m)
#pragma unroll
        for (int n = 0; n < 4; ++n) {
            int orow = i0 + m * 16 + ((l >> 4) << 2);
            int ocol = (w << 6) + (n << 4) + lr;
            float* op = pbase + (size_t)orow * D + ocol;
#pragma unroll
            for (int v = 0; v < 4; ++v) op[(size_t)v * D] = acc[m][n][v];
        }
}

// K7: fused split-K reduce + epilogue
__global__ void k_final2(const float* __restrict__ part, const float* __restrict__ rspart,
                         float* __restrict__ out) {
    __shared__ float sb[4];
    int row = blockIdx.x, t = threadIdx.x;
    float raw = 0.f, rs = 0.f;
#pragma unroll
    for (int kbi = 0; kbi < KSPLIT; ++kbi) {
        raw += part[((size_t)kbi * N_ROWS + row) * D + t];
        rs += rspart[(size_t)kbi * N_ROWS + row];
    }
    float hp = raw / rs;
    float ey = 0.f;
    if (t >= 1) ey = (hp > 0.f) ? hp : expm1f(hp);
    float ss = breduce_sum256(ey * ey, sb);
    float x0 = sqrtf(1.f + ss);
    float th = fmaxf(x0, 1.f + 1e-7f);
    float al = acoshf(th);
    float yn = fmaxf(sqrtf(ss), 1e-15f);
    float u = (t >= 1) ? (al * ey / yn) : 0.f;
    float s = 1.f / (1.f + expf(-u));
    float s2 = (t >= 1) ? s * s : 0.f;
    float ssn = breduce_sum256(s2, sb);
    float xn = fmaxf(sqrtf(ssn), 1e-15f);
    float sh = sinhf(xn);
    float yf = (t >= 1) ? (sh * s / xn) : 0.f;
    float sy = breduce_sum256(yf * yf, sb);
    float res = (t == 0) ? sqrtf(1.f + sy) : yf;
    out[(size_t)row * D + t] = res;
}

extern "C" void kernel_launch(void* const* d_in, const int* in_sizes, int n_in,
                              void* d_out, int out_size, void* d_ws, size_t ws_size,
                              hipStream_t stream) {
    const float* x    = (const float*)d_in[0];
    const int*   adj  = (const int*)d_in[1];
    const float* Wg   = (const float*)d_in[3];
    const float* Wa   = (const float*)d_in[4];
    const float* aatt = (const float*)d_in[5];
    float* out = (float*)d_out;

    char* wsb = (char*)d_ws;
    float*          M2     = (float*)(wsb);                      // 256 KB
    float*          h      = (float*)(wsb + 0x0040000);          // 8 MB (overlaid by part[0])
    float*          part   = (float*)(wsb + 0x0040000);          // 32 MB
    unsigned short* GT     = (unsigned short*)(wsb + 0x2040000); // 4 MB
    float*          wexp   = (float*)(wsb + 0x2440000);          // 32 KB
    float*          rspart = (float*)(wsb + 0x2448000);          // 128 KB
    unsigned short* wbf    = (unsigned short*)(wsb + 0x2468000); // 16 KB

    k_M2<<<255, 256, 0, stream>>>(Wg, Wa, M2);
    k_h<<<N_ROWS / 8, 256, 0, stream>>>(x, M2, aatt, h, wexp, wbf);
    k_makeGT<<<dim3(N_ROWS / 64, 4), 256, 0, stream>>>(h, wexp, GT);
    k_attreg<<<(N_ROWS / 32) * KSPLIT, 256, 0, stream>>>(adj, GT, wbf, part, rspart);
    k_final2<<<N_ROWS, 256, 0, stream>>>(part, rspart, out);
}